// Round 1
// baseline (3331.662 us; speedup 1.0000x reference)
//
#include <hip/hip_runtime.h>
#include <math.h>

#define NB 2
#define NN 2048
#define DD 512

__device__ __forceinline__ float waveReduceSum(float v) {
#pragma unroll
  for (int o = 32; o; o >>= 1) v += __shfl_down(v, o, 64);
  return v;
}
__device__ __forceinline__ float waveReduceMax(float v) {
#pragma unroll
  for (int o = 32; o; o >>= 1) v = fmaxf(v, __shfl_down(v, o, 64));
  return v;
}
// 256-thread block reductions (4 waves). Leading __syncthreads makes repeated
// calls with the same red4 buffer safe.
__device__ __forceinline__ float blockReduceSum(float v, float* red4) {
  int tid = threadIdx.x;
  __syncthreads();
  v = waveReduceSum(v);
  if ((tid & 63) == 0) red4[tid >> 6] = v;
  __syncthreads();
  return red4[0] + red4[1] + red4[2] + red4[3];
}
__device__ __forceinline__ float blockReduceMax(float v, float* red4) {
  int tid = threadIdx.x;
  __syncthreads();
  v = waveReduceMax(v);
  if ((tid & 63) == 0) red4[tid >> 6] = v;
  __syncthreads();
  return fmaxf(fmaxf(red4[0], red4[1]), fmaxf(red4[2], red4[3]));
}

// ---------------- LayerNorm: one block (256 thr) per row of 512 ----------------
__global__ void ln_kernel(const float* __restrict__ x, const float* __restrict__ g,
                          const float* __restrict__ bb, float* __restrict__ y) {
  int row = blockIdx.x;
  const float* xr = x + (size_t)row * DD;
  float* yr = y + (size_t)row * DD;
  int tid = threadIdx.x;
  __shared__ float red4[4];
  float v0 = xr[tid], v1 = xr[tid + 256];
  float s = blockReduceSum(v0 + v1, red4);
  float mu = s * (1.0f / 512.0f);
  float d0 = v0 - mu, d1 = v1 - mu;
  float ss = blockReduceSum(d0 * d0 + d1 * d1, red4);
  float rstd = rsqrtf(ss * (1.0f / 512.0f) + 1e-6f);
  yr[tid] = d0 * rstd * g[tid] + bb[tid];
  yr[tid + 256] = d1 * rstd * g[tid + 256] + bb[tid + 256];
}

// ---------------- fp32 tiled GEMM: C[M,512] = A[M,512] @ W[512,512] ------------
__global__ void gemm_kernel(const float* __restrict__ A, const float* __restrict__ Wm,
                            float* __restrict__ C) {
  __shared__ float As[16][17], Ws[16][17];
  int tx = threadIdx.x, ty = threadIdx.y;
  int row = blockIdx.y * 16 + ty, col = blockIdx.x * 16 + tx;
  float acc = 0.f;
  for (int k0 = 0; k0 < DD; k0 += 16) {
    As[ty][tx] = A[(size_t)row * DD + k0 + tx];
    Ws[ty][tx] = Wm[(size_t)(k0 + ty) * DD + col];
    __syncthreads();
#pragma unroll
    for (int kk = 0; kk < 16; kk++) acc += As[ty][kk] * Ws[kk][tx];
    __syncthreads();
  }
  C[(size_t)row * DD + col] = acc;
}

// ---------------- per-(b,n) head dot products s = h.a_src, t = h.a_dst ---------
__global__ void st_kernel(const float* __restrict__ hbuf, const float* __restrict__ asrc,
                          const float* __restrict__ adst, float* __restrict__ sOut,
                          float* __restrict__ tOut, int Hn, int Dh) {
  int row = blockIdx.x;  // b*NN + n
  int b = row >> 11;
  int n = row & (NN - 1);
  __shared__ float ps[DD], pt[DD], red4[4];
  const float* hr = hbuf + (size_t)row * DD;
  for (int k = threadIdx.x; k < DD; k += 256) {
    float hv = hr[k];
    ps[k] = hv * asrc[k];
    pt[k] = hv * adst[k];
  }
  __syncthreads();
  for (int hh = 0; hh < Hn; hh++) {
    float vs = 0.f, vt = 0.f;
    for (int k = threadIdx.x; k < Dh; k += 256) {
      vs += ps[hh * Dh + k];
      vt += pt[hh * Dh + k];
    }
    vs = blockReduceSum(vs, red4);
    vt = blockReduceSum(vt, red4);
    if (threadIdx.x == 0) {
      sOut[((size_t)b * Hn + hh) * NN + n] = vs;
      tOut[((size_t)b * Hn + hh) * NN + n] = vt;
    }
  }
}

// ---------------- fused attention row kernel -----------------------------------
// h layout: [B, N, Hn, DH]  (natural GEMM output [B*N, D])
// one block (256 thr) per (b, hh, i): e_j = leakyrelu(s_i + t_j) + bias[b,i,j],
// softmax over j in LDS, then out[b,i,hh*DH+k] = sum_j p_j h[b,j,hh,k] * inv + res
template <int DH>
__global__ void attn_kernel(const float* __restrict__ hbuf, const float* __restrict__ bias,
                            const float* __restrict__ sArr, const float* __restrict__ tArr,
                            const float* __restrict__ res, float* __restrict__ out, int Hn) {
  int i = blockIdx.x & (NN - 1);
  int bh = blockIdx.x >> 11;  // b*Hn + hh
  int hh = bh % Hn;
  int b = bh / Hn;
  int tid = threadIdx.x;
  __shared__ float p[NN];
  __shared__ float red4[4];
  __shared__ float red256[256];

  const float* trow = tArr + (size_t)bh * NN;
  const float* brow = bias + ((size_t)b * NN + i) * NN;
  float si = sArr[(size_t)bh * NN + i];

  float lmax = -1e30f;
  for (int j = tid; j < NN; j += 256) {
    float e = si + trow[j];
    e = e > 0.f ? e : 0.2f * e;
    e += brow[j];
    p[j] = e;
    lmax = fmaxf(lmax, e);
  }
  float m = blockReduceMax(lmax, red4);
  float lsum = 0.f;
  for (int j = tid; j < NN; j += 256) {
    float pe = expf(p[j] - m);
    p[j] = pe;
    lsum += pe;
  }
  float sum = blockReduceSum(lsum, red4);
  float inv = 1.0f / sum;
  // p[] writes are visible: each thread wrote before the reduce's syncthreads.

  constexpr int KT = DH < 256 ? DH : 256;  // threads along k
  constexpr int JG = 256 / KT;             // groups along j
  constexpr int KP = (DH + 255) / 256;     // k passes (1 or 2)
  constexpr int JPG = NN / JG;
  int jg = tid / KT, kk = tid % KT;
  float acc[KP];
#pragma unroll
  for (int kp = 0; kp < KP; kp++) acc[kp] = 0.f;
  const float* hbase = hbuf + ((size_t)b * NN * Hn + hh) * DH;
  for (int j = jg * JPG; j < (jg + 1) * JPG; ++j) {
    float pj = p[j];
    const float* hj = hbase + (size_t)j * Hn * DH;
#pragma unroll
    for (int kp = 0; kp < KP; kp++) acc[kp] += pj * hj[kp * KT + kk];
  }
  size_t obase = ((size_t)(b * NN + i)) * DD + (size_t)hh * DH;
  if (JG > 1) {
    red256[tid] = acc[0];
    __syncthreads();
    if (tid < KT) {
      float a = 0.f;
#pragma unroll
      for (int g = 0; g < JG; g++) a += red256[g * KT + tid];
      out[obase + tid] = a * inv + res[obase + tid];
    }
  } else {
#pragma unroll
    for (int kp = 0; kp < KP; kp++) {
      int k = kp * KT + kk;
      out[obase + k] = acc[kp] * inv + res[obase + k];
    }
  }
}

extern "C" void kernel_launch(void* const* d_in, const int* in_sizes, int n_in,
                              void* d_out, int out_size, void* d_ws, size_t ws_size,
                              hipStream_t stream) {
  const float* x = (const float*)d_in[0];
  const float* bias = (const float*)d_in[1];
  const float* W1 = (const float*)d_in[2];
  const float* asrc1 = (const float*)d_in[3];
  const float* adst1 = (const float*)d_in[4];
  const float* g1 = (const float*)d_in[5];
  const float* b1 = (const float*)d_in[6];
  const float* W2 = (const float*)d_in[7];
  const float* asrc2 = (const float*)d_in[8];
  const float* adst2 = (const float*)d_in[9];
  const float* g2 = (const float*)d_in[10];
  const float* b2 = (const float*)d_in[11];
  float* out = (float*)d_out;
  float* ws = (float*)d_ws;

  const size_t RC = (size_t)NB * NN * DD;  // 2097152 floats
  float* lnBuf = ws;                       // reused by both layers
  float* hBuf = ws + RC;                   // h1 then h2
  float* attnBuf = ws + 2 * RC;            // layer-1 output (residual for layer 2)
  float* sBuf = ws + 3 * RC;
  float* tBuf = sBuf + (size_t)NB * 8 * NN;

  const int rows = NB * NN;  // 4096
  dim3 gblk(16, 16);
  dim3 ggrid(DD / 16, rows / 16);

  // ---- layer 1 (H=8, Dh=64) ----
  hipLaunchKernelGGL(ln_kernel, dim3(rows), dim3(256), 0, stream, x, g1, b1, lnBuf);
  hipLaunchKernelGGL(gemm_kernel, ggrid, gblk, 0, stream, lnBuf, W1, hBuf);
  hipLaunchKernelGGL(st_kernel, dim3(rows), dim3(256), 0, stream, hBuf, asrc1, adst1, sBuf,
                     tBuf, 8, 64);
  hipLaunchKernelGGL(attn_kernel<64>, dim3(NB * 8 * NN), dim3(256), 0, stream, hBuf, bias,
                     sBuf, tBuf, x, attnBuf, 8);

  // ---- layer 2 (H=1, Dh=512) ----
  hipLaunchKernelGGL(ln_kernel, dim3(rows), dim3(256), 0, stream, attnBuf, g2, b2, lnBuf);
  hipLaunchKernelGGL(gemm_kernel, ggrid, gblk, 0, stream, lnBuf, W2, hBuf);
  hipLaunchKernelGGL(st_kernel, dim3(rows), dim3(256), 0, stream, hBuf, asrc2, adst2, sBuf,
                     tBuf, 1, 512);
  hipLaunchKernelGGL(attn_kernel<512>, dim3(NB * 1 * NN), dim3(256), 0, stream, hBuf, bias,
                     sBuf, tBuf, attnBuf, out, 1);
}

// Round 2
// 348.402 us; speedup vs baseline: 9.5627x; 9.5627x over previous
//
#include <hip/hip_runtime.h>
#include <math.h>

#define NB 2
#define NN 2048
#define DD 512

typedef __attribute__((ext_vector_type(8))) short short8;
typedef __attribute__((ext_vector_type(4))) float f32x4;

__device__ __forceinline__ float waveReduceSum(float v) {
#pragma unroll
  for (int o = 32; o; o >>= 1) v += __shfl_down(v, o, 64);
  return v;
}
__device__ __forceinline__ float waveReduceMax(float v) {
#pragma unroll
  for (int o = 32; o; o >>= 1) v = fmaxf(v, __shfl_down(v, o, 64));
  return v;
}
__device__ __forceinline__ float blockReduceSum(float v, float* red4) {
  int tid = threadIdx.x;
  __syncthreads();
  v = waveReduceSum(v);
  if ((tid & 63) == 0) red4[tid >> 6] = v;
  __syncthreads();
  return red4[0] + red4[1] + red4[2] + red4[3];
}
__device__ __forceinline__ float blockReduceMax(float v, float* red4) {
  int tid = threadIdx.x;
  __syncthreads();
  v = waveReduceMax(v);
  if ((tid & 63) == 0) red4[tid >> 6] = v;
  __syncthreads();
  return fmaxf(fmaxf(red4[0], red4[1]), fmaxf(red4[2], red4[3]));
}

__device__ __forceinline__ unsigned short f2bf(float x) {
  union { float f; unsigned u; } a;
  a.f = x;
  unsigned r = a.u + 0x7FFF + ((a.u >> 16) & 1);  // RNE
  return (unsigned short)(r >> 16);
}

// ---------------- LayerNorm: one block (256 thr) per row of 512 ----------------
__global__ __launch_bounds__(256) void ln_kernel(const float* __restrict__ x,
                                                 const float* __restrict__ g,
                                                 const float* __restrict__ bb,
                                                 float* __restrict__ y) {
  int row = blockIdx.x;
  const float* xr = x + (size_t)row * DD;
  float* yr = y + (size_t)row * DD;
  int tid = threadIdx.x;
  __shared__ float red4[4];
  float v0 = xr[tid], v1 = xr[tid + 256];
  float s = blockReduceSum(v0 + v1, red4);
  float mu = s * (1.0f / 512.0f);
  float d0 = v0 - mu, d1 = v1 - mu;
  float ss = blockReduceSum(d0 * d0 + d1 * d1, red4);
  float rstd = rsqrtf(ss * (1.0f / 512.0f) + 1e-6f);
  yr[tid] = d0 * rstd * g[tid] + bb[tid];
  yr[tid + 256] = d1 * rstd * g[tid + 256] + bb[tid + 256];
}

// ---------------- fp32 GEMM: C[4096,512] = A[4096,512] @ W[512,512] ------------
// 64x64 block tile, 4x4 register micro-tile, K-step 16.
__global__ __launch_bounds__(256) void gemm_kernel(const float* __restrict__ A,
                                                   const float* __restrict__ Wm,
                                                   float* __restrict__ C) {
  __shared__ float As[16][68];  // [k][m], pad to 68 for alignment+banks
  __shared__ float Ws[16][64];  // [k][n]
  int t = threadIdx.x;
  int tx = t & 15, ty = t >> 4;
  int row0 = blockIdx.y * 64, col0 = blockIdx.x * 64;
  float acc[4][4] = {};
  for (int k0 = 0; k0 < DD; k0 += 16) {
#pragma unroll
    for (int u = 0; u < 4; u++) {
      int ii = (t >> 4) + u * 16;
      As[t & 15][ii] = A[((size_t)row0 + ii) * DD + k0 + (t & 15)];
    }
#pragma unroll
    for (int u = 0; u < 4; u++) {
      int kk = (t >> 6) + u * 4;
      Ws[kk][t & 63] = Wm[((size_t)k0 + kk) * DD + col0 + (t & 63)];
    }
    __syncthreads();
#pragma unroll
    for (int kk = 0; kk < 16; kk++) {
      float av[4], wv[4];
      *(float4*)av = *(const float4*)&As[kk][ty * 4];
      *(float4*)wv = *(const float4*)&Ws[kk][tx * 4];
#pragma unroll
      for (int ui = 0; ui < 4; ui++)
#pragma unroll
        for (int uj = 0; uj < 4; uj++) acc[ui][uj] += av[ui] * wv[uj];
    }
    __syncthreads();
  }
#pragma unroll
  for (int ui = 0; ui < 4; ui++)
#pragma unroll
    for (int uj = 0; uj < 4; uj++)
      C[((size_t)row0 + ty * 4 + ui) * DD + col0 + tx * 4 + uj] = acc[ui][uj];
}

// ---------------- per-(b,n) head dot products s = h.a_src, t = h.a_dst ---------
__global__ __launch_bounds__(256) void st_kernel(const float* __restrict__ hbuf,
                                                 const float* __restrict__ asrc,
                                                 const float* __restrict__ adst,
                                                 float* __restrict__ sOut,
                                                 float* __restrict__ tOut, int Hn, int Dh) {
  int row = blockIdx.x;  // b*NN + n
  int b = row >> 11;
  int n = row & (NN - 1);
  __shared__ float ps[DD], pt[DD], red4[4];
  const float* hr = hbuf + (size_t)row * DD;
  for (int k = threadIdx.x; k < DD; k += 256) {
    float hv = hr[k];
    ps[k] = hv * asrc[k];
    pt[k] = hv * adst[k];
  }
  __syncthreads();
  for (int hh = 0; hh < Hn; hh++) {
    float vs = 0.f, vt = 0.f;
    for (int k = threadIdx.x; k < Dh; k += 256) {
      vs += ps[hh * Dh + k];
      vt += pt[hh * Dh + k];
    }
    vs = blockReduceSum(vs, red4);
    vt = blockReduceSum(vt, red4);
    if (threadIdx.x == 0) {
      sOut[((size_t)b * Hn + hh) * NN + n] = vs;
      tOut[((size_t)b * Hn + hh) * NN + n] = vt;
    }
  }
}

// ---------------- softmax row stats: m_i and 1/sum per (b,h,i) ------------------
__global__ __launch_bounds__(256) void stats_kernel(const float* __restrict__ bias,
                                                    const float* __restrict__ sArr,
                                                    const float* __restrict__ tArr,
                                                    float* __restrict__ mArr,
                                                    float* __restrict__ invArr, int Hn) {
  int row = blockIdx.x;  // b*NN + i
  int b = row >> 11, i = row & (NN - 1);
  int t = threadIdx.x;
  __shared__ float bs[NN];
  __shared__ float red4[4];
  const float* brow = bias + ((size_t)b * NN + i) * NN;
  for (int j = t; j < NN; j += 256) bs[j] = brow[j];
  __syncthreads();
  for (int h = 0; h < Hn; h++) {
    size_t bhN = ((size_t)b * Hn + h) * NN;
    float si = sArr[bhN + i];
    const float* trow = tArr + bhN;
    float lm = -1e30f;
    for (int j = t; j < NN; j += 256) {
      float e = si + trow[j];
      e = e > 0.f ? e : 0.2f * e;
      e += bs[j];
      lm = fmaxf(lm, e);
    }
    float m = blockReduceMax(lm, red4);
    float ls = 0.f;
    for (int j = t; j < NN; j += 256) {
      float e = si + trow[j];
      e = e > 0.f ? e : 0.2f * e;
      e += bs[j];
      ls += __expf(e - m);
    }
    float s = blockReduceSum(ls, red4);
    if (t == 0) {
      mArr[bhN + i] = m;
      invArr[bhN + i] = 1.0f / s;
    }
  }
}

// ---------------- transpose+convert: hbT[b][c][j] = bf16(h[b][j][c]) ------------
__global__ __launch_bounds__(256) void conv_kernel(const float* __restrict__ hbuf,
                                                   unsigned short* __restrict__ hbT) {
  __shared__ float tile[64][65];
  int j0 = blockIdx.x * 64, c0 = blockIdx.y * 64, b = blockIdx.z;
  int t = threadIdx.x;
#pragma unroll
  for (int u = 0; u < 16; u++) {
    int idx = t + u * 256;
    int jl = idx >> 6, cl = idx & 63;
    tile[jl][cl] = hbuf[((size_t)b * NN + j0 + jl) * DD + c0 + cl];
  }
  __syncthreads();
#pragma unroll
  for (int u = 0; u < 16; u++) {
    int idx = t + u * 256;
    int cl = idx >> 6, jl = idx & 63;
    hbT[((size_t)b * DD + c0 + cl) * NN + j0 + jl] = f2bf(tile[jl][cl]);
  }
}

// ---------------- PV via MFMA: out tile 32 rows x 64 cols per block -------------
// P computed on the fly into LDS (bf16); V read as B-fragments straight from hbT.
__global__ __launch_bounds__(256) void pv_kernel(
    const unsigned short* __restrict__ hbT, const float* __restrict__ bias,
    const float* __restrict__ sArr, const float* __restrict__ tArr,
    const float* __restrict__ mArr, const float* __restrict__ invArr,
    const float* __restrict__ res, float* __restrict__ out, int Hn, int Dh, int chunks) {
  __shared__ unsigned short pT[32][40];  // [i][k], +8 pad: rows 80B (16B-aligned)
  int t = threadIdx.x;
  int it = blockIdx.x & 63;  // NN/32 i-tiles
  int r = blockIdx.x >> 6;
  int ck = r % chunks;
  int bh = r / chunks;
  int h = bh % Hn;
  int b = bh / Hn;
  int i0 = it * 32;
  int c0 = h * Dh + ck * 64;

  int iloc = t >> 3;
  int i = i0 + iloc;
  size_t bhN = (size_t)bh * NN;
  float si = sArr[bhN + i];
  float mi = mArr[bhN + i];
  float inv = invArr[bhN + i];
  int jb = (t & 7) * 4;

  const float* brow = bias + ((size_t)b * NN + i) * NN;
  const float* trow = tArr + bhN;

  int w = t >> 6, l = t & 63;
  int wr = w >> 1, wc = w & 1;
  const unsigned short* hb0 =
      hbT + ((size_t)b * DD + c0 + wc * 32 + (l & 15)) * NN + ((l >> 4) * 8);
  const unsigned short* hb1 = hb0 + (size_t)16 * NN;

  f32x4 acc0 = {0.f, 0.f, 0.f, 0.f}, acc1 = {0.f, 0.f, 0.f, 0.f};

  for (int j0 = 0; j0 < NN; j0 += 32) {
    float4 tv = *(const float4*)&trow[j0 + jb];
    float4 bv = *(const float4*)&brow[j0 + jb];
    float e0 = si + tv.x; e0 = e0 > 0.f ? e0 : 0.2f * e0; e0 += bv.x;
    float e1 = si + tv.y; e1 = e1 > 0.f ? e1 : 0.2f * e1; e1 += bv.y;
    float e2 = si + tv.z; e2 = e2 > 0.f ? e2 : 0.2f * e2; e2 += bv.z;
    float e3 = si + tv.w; e3 = e3 > 0.f ? e3 : 0.2f * e3; e3 += bv.w;
    ushort4 pk;
    pk.x = f2bf(__expf(e0 - mi) * inv);
    pk.y = f2bf(__expf(e1 - mi) * inv);
    pk.z = f2bf(__expf(e2 - mi) * inv);
    pk.w = f2bf(__expf(e3 - mi) * inv);
    *(ushort4*)&pT[iloc][jb] = pk;
    __syncthreads();
    short8 a = *(const short8*)&pT[wr * 16 + (l & 15)][(l >> 4) * 8];
    short8 b0 = *(const short8*)(hb0 + j0);
    short8 b1 = *(const short8*)(hb1 + j0);
    acc0 = __builtin_amdgcn_mfma_f32_16x16x32_bf16(a, b0, acc0, 0, 0, 0);
    acc1 = __builtin_amdgcn_mfma_f32_16x16x32_bf16(a, b1, acc1, 0, 0, 0);
    __syncthreads();
  }

  int orow = i0 + wr * 16 + (l >> 4) * 4;
  int oc = c0 + wc * 32 + (l & 15);
#pragma unroll
  for (int reg = 0; reg < 4; reg++) {
    size_t idx = ((size_t)b * NN + orow + reg) * DD + oc;
    out[idx] = acc0[reg] + res[idx];
    out[idx + 16] = acc1[reg] + res[idx + 16];
  }
}

extern "C" void kernel_launch(void* const* d_in, const int* in_sizes, int n_in,
                              void* d_out, int out_size, void* d_ws, size_t ws_size,
                              hipStream_t stream) {
  const float* x = (const float*)d_in[0];
  const float* bias = (const float*)d_in[1];
  const float* W1 = (const float*)d_in[2];
  const float* asrc1 = (const float*)d_in[3];
  const float* adst1 = (const float*)d_in[4];
  const float* g1 = (const float*)d_in[5];
  const float* b1 = (const float*)d_in[6];
  const float* W2 = (const float*)d_in[7];
  const float* asrc2 = (const float*)d_in[8];
  const float* adst2 = (const float*)d_in[9];
  const float* g2 = (const float*)d_in[10];
  const float* b2 = (const float*)d_in[11];
  float* out = (float*)d_out;
  float* ws = (float*)d_ws;

  const size_t RC = (size_t)NB * NN * DD;  // 2097152 floats (8 MB)
  float* lnBuf = ws;                       // 8 MB; lower 4 MB later reused as hbT
  float* hBuf = ws + RC;
  float* attnBuf = ws + 2 * RC;
  // s/t/m/inv live in upper half of lnBuf slot (dead after each gemm)
  float* sBuf = ws + RC / 2;
  float* tBuf = sBuf + (size_t)NB * 8 * NN;
  float* mArr = tBuf + (size_t)NB * 8 * NN;
  float* invArr = mArr + (size_t)NB * 8 * NN;
  unsigned short* hbT = (unsigned short*)ws;  // 4 MB, overlays lnBuf[0 : RC/2)

  const int rows = NB * NN;  // 4096
  dim3 ggrid(DD / 64, rows / 64);
  dim3 cgrid(NN / 64, DD / 64, NB);

  // ---- layer 1 (H=8, Dh=64) ----
  hipLaunchKernelGGL(ln_kernel, dim3(rows), dim3(256), 0, stream, x, g1, b1, lnBuf);
  hipLaunchKernelGGL(gemm_kernel, ggrid, dim3(256), 0, stream, lnBuf, W1, hBuf);
  hipLaunchKernelGGL(st_kernel, dim3(rows), dim3(256), 0, stream, hBuf, asrc1, adst1, sBuf,
                     tBuf, 8, 64);
  hipLaunchKernelGGL(stats_kernel, dim3(rows), dim3(256), 0, stream, bias, sBuf, tBuf, mArr,
                     invArr, 8);
  hipLaunchKernelGGL(conv_kernel, cgrid, dim3(256), 0, stream, hBuf, hbT);
  hipLaunchKernelGGL(pv_kernel, dim3(64 * 1 * NB * 8), dim3(256), 0, stream, hbT, bias, sBuf,
                     tBuf, mArr, invArr, x, attnBuf, 8, 64, 1);

  // ---- layer 2 (H=1, Dh=512) ----
  hipLaunchKernelGGL(ln_kernel, dim3(rows), dim3(256), 0, stream, attnBuf, g2, b2, lnBuf);
  hipLaunchKernelGGL(gemm_kernel, ggrid, dim3(256), 0, stream, lnBuf, W2, hBuf);
  hipLaunchKernelGGL(st_kernel, dim3(rows), dim3(256), 0, stream, hBuf, asrc2, adst2, sBuf,
                     tBuf, 1, 512);
  hipLaunchKernelGGL(stats_kernel, dim3(rows), dim3(256), 0, stream, bias, sBuf, tBuf, mArr,
                     invArr, 1);
  hipLaunchKernelGGL(conv_kernel, cgrid, dim3(256), 0, stream, hBuf, hbT);
  hipLaunchKernelGGL(pv_kernel, dim3(64 * 8 * NB * 1), dim3(256), 0, stream, hbT, bias, sBuf,
                     tBuf, mArr, invArr, attnBuf, out, 1, 512, 8);
}

// Round 3
// 310.577 us; speedup vs baseline: 10.7273x; 1.1218x over previous
//
#include <hip/hip_runtime.h>
#include <math.h>

#define NB 2
#define NN 2048
#define DD 512

typedef __attribute__((ext_vector_type(8))) short short8;
typedef __attribute__((ext_vector_type(4))) float f32x4;

__device__ __forceinline__ unsigned short f2bf(float x) {
  union { float f; unsigned u; } a;
  a.f = x;
  unsigned r = a.u + 0x7FFF + ((a.u >> 16) & 1);  // RNE
  return (unsigned short)(r >> 16);
}
__device__ __forceinline__ float bf2f(unsigned short u) {
  union { unsigned u; float f; } a;
  a.u = ((unsigned)u) << 16;
  return a.f;
}

__device__ __forceinline__ float waveReduceSum(float v) {
#pragma unroll
  for (int o = 32; o; o >>= 1) v += __shfl_down(v, o, 64);
  return v;
}
__device__ __forceinline__ float blockReduceSum(float v, float* red4) {
  int tid = threadIdx.x;
  __syncthreads();
  v = waveReduceSum(v);
  if ((tid & 63) == 0) red4[tid >> 6] = v;
  __syncthreads();
  return red4[0] + red4[1] + red4[2] + red4[3];
}

// ---------------- LayerNorm -> bf16: one block (256 thr) per row of 512 --------
__global__ __launch_bounds__(256) void ln_kernel(const float* __restrict__ x,
                                                 const float* __restrict__ g,
                                                 const float* __restrict__ bb,
                                                 unsigned short* __restrict__ y) {
  int row = blockIdx.x;
  int t = threadIdx.x;
  const float* xr = x + (size_t)row * DD;
  __shared__ float red4[4];
  float2 v = *(const float2*)&xr[2 * t];
  float s = blockReduceSum(v.x + v.y, red4);
  float mu = s * (1.0f / 512.0f);
  float d0 = v.x - mu, d1 = v.y - mu;
  float ss = blockReduceSum(d0 * d0 + d1 * d1, red4);
  float rstd = rsqrtf(ss * (1.0f / 512.0f) + 1e-6f);
  float2 gg = *(const float2*)&g[2 * t];
  float2 bv = *(const float2*)&bb[2 * t];
  ushort2 o;
  o.x = f2bf(d0 * rstd * gg.x + bv.x);
  o.y = f2bf(d1 * rstd * gg.y + bv.y);
  *(ushort2*)&y[(size_t)row * DD + 2 * t] = o;
}

// ---------------- W [512k][512c] fp32 -> WT [c][k] bf16 ------------------------
__global__ __launch_bounds__(256) void wt_kernel(const float* __restrict__ W,
                                                 unsigned short* __restrict__ WT) {
  __shared__ float tile[64][65];
  int kt = blockIdx.x * 64, ct = blockIdx.y * 64;
  int t = threadIdx.x;
#pragma unroll
  for (int u = 0; u < 16; u++) {
    int lin = t + u * 256;
    int kl = lin >> 6, cl = lin & 63;
    tile[kl][cl] = W[(size_t)(kt + kl) * DD + ct + cl];
  }
  __syncthreads();
#pragma unroll
  for (int u = 0; u < 16; u++) {
    int lin = t + u * 256;
    int cl = lin >> 6, kl = lin & 63;
    WT[(size_t)(ct + cl) * DD + kt + kl] = f2bf(tile[kl][cl]);
  }
}

// ---------------- v = W @ a  (per head): vs/vd are [H][512] fp32 ---------------
__global__ __launch_bounds__(256) void v_kernel(const float* __restrict__ W,
                                                const float* __restrict__ asrc,
                                                const float* __restrict__ adst,
                                                float* __restrict__ vs,
                                                float* __restrict__ vd, int HN, int Dh) {
  int t = threadIdx.x;
  int dl = t >> 2, kq = t & 3;
  int d = blockIdx.x * 64 + dl;
  int kn = Dh >> 2;
  for (int h = 0; h < HN; h++) {
    const float* wr = W + (size_t)d * DD + h * Dh + kq * kn;
    const float* as = asrc + h * Dh + kq * kn;
    const float* ad = adst + h * Dh + kq * kn;
    float s = 0.f, dd2 = 0.f;
    for (int k = 0; k < kn; k++) {
      float wv = wr[k];
      s += wv * as[k];
      dd2 += wv * ad[k];
    }
    s += __shfl_xor(s, 1);
    s += __shfl_xor(s, 2);
    dd2 += __shfl_xor(dd2, 1);
    dd2 += __shfl_xor(dd2, 2);
    if (kq == 0) {
      vs[(size_t)h * DD + d] = s;
      vd[(size_t)h * DD + d] = dd2;
    }
  }
}

// ---------------- bf16 MFMA GEMM: hbT[b][c][j] = bf16( lnB @ W ) ---------------
// 64 rows x 64 cols per block, 4 waves (16 rows each), K=512 direct from global.
__global__ __launch_bounds__(256) void gemm_kernel(const unsigned short* __restrict__ A,
                                                   const unsigned short* __restrict__ BT,
                                                   unsigned short* __restrict__ hbT) {
  __shared__ unsigned short tl[64][76];
  int t = threadIdx.x, w = t >> 6, l = t & 63;
  int li = l & 15, lg = l >> 4;
  int R0 = blockIdx.x * 64;  // global row base (b*NN + j), 64 | 2048
  int c0 = blockIdx.y * 64;
  const unsigned short* ar = A + (size_t)(R0 + w * 16 + li) * DD + lg * 8;
  const unsigned short* br = BT + (size_t)(c0 + li) * DD + lg * 8;
  f32x4 acc[4] = {};
#pragma unroll
  for (int k0 = 0; k0 < DD; k0 += 32) {
    short8 af = *(const short8*)(ar + k0);
#pragma unroll
    for (int f = 0; f < 4; f++) {
      short8 bf = *(const short8*)(br + (size_t)f * 16 * DD + k0);
      acc[f] = __builtin_amdgcn_mfma_f32_16x16x32_bf16(af, bf, acc[f], 0, 0, 0);
    }
  }
#pragma unroll
  for (int f = 0; f < 4; f++)
#pragma unroll
    for (int r = 0; r < 4; r++) tl[f * 16 + li][w * 16 + lg * 4 + r] = f2bf(acc[f][r]);
  __syncthreads();
  int b = R0 >> 11, jb0 = R0 & (NN - 1);
#pragma unroll
  for (int u = 0; u < 2; u++) {
    int lin = t + u * 256;
    int cl = lin >> 3, jc = lin & 7;
    union { short8 v; ushort4 h[2]; } o;
    o.h[0] = *(const ushort4*)&tl[cl][jc * 8];
    o.h[1] = *(const ushort4*)&tl[cl][jc * 8 + 4];
    *(short8*)(hbT + ((size_t)b * DD + c0 + cl) * NN + jb0 + jc * 8) = o.v;
  }
}

// ---------------- s,t: wave per row; s = lnrow . vs[h], t = lnrow . vd[h] ------
__global__ __launch_bounds__(256) void st_kernel(const unsigned short* __restrict__ lnB,
                                                 const float* __restrict__ vs,
                                                 const float* __restrict__ vd,
                                                 float* __restrict__ sOut,
                                                 float* __restrict__ tOut, int HN) {
  int t = threadIdx.x, w = t >> 6, l = t & 63;
  int row = blockIdx.x * 4 + w;
  int b = row >> 11, n = row & (NN - 1);
  const unsigned short* lr = lnB + (size_t)row * DD + l * 8;
  union { short8 v; unsigned short u[8]; } xv;
  xv.v = *(const short8*)lr;
  float xf[8];
#pragma unroll
  for (int k = 0; k < 8; k++) xf[k] = bf2f(xv.u[k]);
  for (int h = 0; h < HN; h++) {
    const float* vsr = vs + (size_t)h * DD + l * 8;
    const float* vdr = vd + (size_t)h * DD + l * 8;
    float4 a0 = *(const float4*)vsr, a1 = *(const float4*)(vsr + 4);
    float4 c0 = *(const float4*)vdr, c1 = *(const float4*)(vdr + 4);
    float ps = xf[0] * a0.x + xf[1] * a0.y + xf[2] * a0.z + xf[3] * a0.w +
               xf[4] * a1.x + xf[5] * a1.y + xf[6] * a1.z + xf[7] * a1.w;
    float pd = xf[0] * c0.x + xf[1] * c0.y + xf[2] * c0.z + xf[3] * c0.w +
               xf[4] * c1.x + xf[5] * c1.y + xf[6] * c1.z + xf[7] * c1.w;
#pragma unroll
    for (int o = 32; o; o >>= 1) {
      ps += __shfl_xor(ps, o);
      pd += __shfl_xor(pd, o);
    }
    if (l == 0) {
      sOut[((size_t)b * HN + h) * NN + n] = ps;
      tOut[((size_t)b * HN + h) * NN + n] = pd;
    }
  }
}

// ---------------- fused flash-style PV, P in registers, no LDS, no barriers ----
// Block: 4 waves, wave w owns rows it*64+w*16 .. +16, cols c0..c0+64.
// Lane l computes P[row=l&15][j=(l>>4)*8..+8] straight into the MFMA A-fragment.
// Online softmax with defer-threshold 8 (rescale redistributed via shfl).
template <int HN>
__global__ __launch_bounds__(256) void pv_kernel(const unsigned short* __restrict__ hbT,
                                                 const float* __restrict__ bias,
                                                 const float* __restrict__ sArr,
                                                 const float* __restrict__ tArr,
                                                 const float* __restrict__ res,
                                                 float* __restrict__ out) {
  constexpr int DH = DD / HN;
  int t = threadIdx.x, w = t >> 6, l = t & 63;
  int li = l & 15, lg = l >> 4;
  int it = blockIdx.x;
  int ck = blockIdx.y;
  int bh = blockIdx.z;
  int h = bh % HN, b = bh / HN;
  int iw = it * 64 + w * 16;
  int c0 = h * DH + ck * 64;
  int i = iw + li;
  size_t bhN = (size_t)bh * NN;
  float si = sArr[bhN + i];
  const float* trow = tArr + bhN;
  const float* brow = bias + ((size_t)b * NN + i) * NN;
  const unsigned short* vb = hbT + ((size_t)b * DD + c0 + li) * NN + lg * 8;

  f32x4 acc[4] = {};
  float msum = 0.f, mrun = -1e30f;

  for (int j0 = 0; j0 < NN; j0 += 32) {
    int jb = j0 + lg * 8;
    float4 t0 = *(const float4*)&trow[jb];
    float4 t1 = *(const float4*)&trow[jb + 4];
    float4 b0 = *(const float4*)&brow[jb];
    float4 b1 = *(const float4*)&brow[jb + 4];
    float e[8];
    e[0] = si + t0.x; e[1] = si + t0.y; e[2] = si + t0.z; e[3] = si + t0.w;
    e[4] = si + t1.x; e[5] = si + t1.y; e[6] = si + t1.z; e[7] = si + t1.w;
#pragma unroll
    for (int k = 0; k < 8; k++) e[k] = fmaxf(e[k], 0.2f * e[k]);  // leaky relu
    e[0] += b0.x; e[1] += b0.y; e[2] += b0.z; e[3] += b0.w;
    e[4] += b1.x; e[5] += b1.y; e[6] += b1.z; e[7] += b1.w;
    float tm = fmaxf(fmaxf(fmaxf(e[0], e[1]), fmaxf(e[2], e[3])),
                     fmaxf(fmaxf(e[4], e[5]), fmaxf(e[6], e[7])));
    tm = fmaxf(tm, __shfl_xor(tm, 16));
    tm = fmaxf(tm, __shfl_xor(tm, 32));  // row max of this tile (synced per row)
    if (!__all(tm - mrun <= 8.0f)) {
      float mnew = fmaxf(mrun, tm);
      float sc = __expf(mrun - mnew);  // first tile: exp(-huge)=0 zeroes state
      msum *= sc;
      mrun = mnew;
      float s0 = __shfl(sc, lg * 4 + 0);
      float s1 = __shfl(sc, lg * 4 + 1);
      float s2 = __shfl(sc, lg * 4 + 2);
      float s3 = __shfl(sc, lg * 4 + 3);
#pragma unroll
      for (int f = 0; f < 4; f++) {
        acc[f][0] *= s0; acc[f][1] *= s1; acc[f][2] *= s2; acc[f][3] *= s3;
      }
    }
    union { short8 v; unsigned short u[8]; } a;
    float lsum = 0.f;
#pragma unroll
    for (int k = 0; k < 8; k++) {
      float p = __expf(e[k] - mrun);
      lsum += p;
      a.u[k] = f2bf(p);
    }
    msum += lsum;
#pragma unroll
    for (int f = 0; f < 4; f++) {
      short8 bf = *(const short8*)(vb + (size_t)f * 16 * NN + j0);
      acc[f] = __builtin_amdgcn_mfma_f32_16x16x32_bf16(a.v, bf, acc[f], 0, 0, 0);
    }
  }
  float stot = msum + __shfl_xor(msum, 16);
  stot += __shfl_xor(stot, 32);
  float inv = 1.0f / stot;
  float i0 = __shfl(inv, lg * 4 + 0);
  float i1 = __shfl(inv, lg * 4 + 1);
  float i2 = __shfl(inv, lg * 4 + 2);
  float i3 = __shfl(inv, lg * 4 + 3);
  int gr = iw + lg * 4;
#pragma unroll
  for (int f = 0; f < 4; f++) {
    int gc = c0 + f * 16 + li;
    size_t ix = ((size_t)b * NN + gr) * DD + gc;
    out[ix] = acc[f][0] * i0 + res[ix];
    out[ix + DD] = acc[f][1] * i1 + res[ix + DD];
    out[ix + 2 * DD] = acc[f][2] * i2 + res[ix + 2 * DD];
    out[ix + 3 * DD] = acc[f][3] * i3 + res[ix + 3 * DD];
  }
}

extern "C" void kernel_launch(void* const* d_in, const int* in_sizes, int n_in,
                              void* d_out, int out_size, void* d_ws, size_t ws_size,
                              hipStream_t stream) {
  const float* x = (const float*)d_in[0];
  const float* bias = (const float*)d_in[1];
  const float* W1 = (const float*)d_in[2];
  const float* asrc1 = (const float*)d_in[3];
  const float* adst1 = (const float*)d_in[4];
  const float* g1 = (const float*)d_in[5];
  const float* b1 = (const float*)d_in[6];
  const float* W2 = (const float*)d_in[7];
  const float* asrc2 = (const float*)d_in[8];
  const float* adst2 = (const float*)d_in[9];
  const float* g2 = (const float*)d_in[10];
  const float* b2 = (const float*)d_in[11];
  float* out = (float*)d_out;
  float* ws = (float*)d_ws;

  const size_t RC = (size_t)NB * NN * DD;  // 2097152
  float* attnBuf = ws;                             // 8 MB fp32
  unsigned short* lnB = (unsigned short*)(ws + RC);        // 4 MB bf16
  unsigned short* hbT = (unsigned short*)(ws + RC + RC / 2);  // 4 MB bf16
  unsigned short* WT1 = (unsigned short*)(ws + 2 * RC);    // 0.5 MB
  unsigned short* WT2 = WT1 + (size_t)DD * DD;             // 0.5 MB
  float* vs1 = (float*)(WT2 + (size_t)DD * DD);            // [8][512]
  float* vd1 = vs1 + 8 * DD;
  float* vs2 = vd1 + 8 * DD;  // [1][512]
  float* vd2 = vs2 + DD;
  float* sBuf = vd2 + DD;     // [16][2048]
  float* tBuf = sBuf + 16 * NN;

  const int rows = NB * NN;  // 4096

  // ---- input prep (no deps on x) ----
  hipLaunchKernelGGL(wt_kernel, dim3(8, 8), dim3(256), 0, stream, W1, WT1);
  hipLaunchKernelGGL(wt_kernel, dim3(8, 8), dim3(256), 0, stream, W2, WT2);
  hipLaunchKernelGGL(v_kernel, dim3(8), dim3(256), 0, stream, W1, asrc1, adst1, vs1, vd1, 8, 64);
  hipLaunchKernelGGL(v_kernel, dim3(8), dim3(256), 0, stream, W2, asrc2, adst2, vs2, vd2, 1, 512);

  // ---- layer 1 (H=8, Dh=64) ----
  hipLaunchKernelGGL(ln_kernel, dim3(rows), dim3(256), 0, stream, x, g1, b1, lnB);
  hipLaunchKernelGGL(gemm_kernel, dim3(64, 8), dim3(256), 0, stream, lnB, WT1, hbT);
  hipLaunchKernelGGL(st_kernel, dim3(rows / 4), dim3(256), 0, stream, lnB, vs1, vd1, sBuf, tBuf, 8);
  hipLaunchKernelGGL(pv_kernel<8>, dim3(32, 1, 16), dim3(256), 0, stream, hbT, bias, sBuf, tBuf,
                     x, attnBuf);

  // ---- layer 2 (H=1, Dh=512) ----
  hipLaunchKernelGGL(ln_kernel, dim3(rows), dim3(256), 0, stream, attnBuf, g2, b2, lnB);
  hipLaunchKernelGGL(gemm_kernel, dim3(64, 8), dim3(256), 0, stream, lnB, WT2, hbT);
  hipLaunchKernelGGL(st_kernel, dim3(rows / 4), dim3(256), 0, stream, lnB, vs2, vd2, sBuf, tBuf, 1);
  hipLaunchKernelGGL(pv_kernel<1>, dim3(32, 8, 2), dim3(256), 0, stream, hbT, bias, sBuf, tBuf,
                     attnBuf, out);
}